// Round 3
// baseline (86.558 us; speedup 1.0000x reference)
//
#include <hip/hip_runtime.h>

// VectorQuantizer forward:
//   x          [64,32,32,64] f32  -> flat [N=65536, D=64]
//   embeddings [D=64, K=512] f32  (codes are COLUMNS)
//   out        = x + (q - x)  where q = column argmin_k ||f - e_k||^2
//   loss       = (1 + 0.25) * mean((q - x)^2)
// d_out = [out (4194304 f32), loss (1 f32)]

#define N_ROWS 65536
#define DIM 64
#define KCODES 512
#define KGROUPS 8
#define KCHUNK 64           // codes per wave
#define ROWS_PER_BLOCK 64   // 1 row per lane; 8 waves K-split the codebook

typedef float f32x2 __attribute__((ext_vector_type(2)));

// ws layout (bytes):
//   [0,8)      double loss accumulator
//   [256,2304) en2[512] f32
//   [4096, 4096+131072) eT[512][64] f32

__global__ void vq_prep(const float* __restrict__ emb, float* __restrict__ ws_f,
                        double* __restrict__ ws_d) {
    int k = threadIdx.x;  // 512 threads, one per code
    if (k == 0) ws_d[0] = 0.0;
    float* en2 = ws_f + 64;    // byte offset 256
    float* eT  = ws_f + 1024;  // byte offset 4096
    float s = 0.0f;
    #pragma unroll
    for (int d = 0; d < DIM; ++d) {
        float v = emb[d * KCODES + k];   // coalesced across k
        eT[k * DIM + d] = v;
        s = fmaf(v, v, s);
    }
    en2[k] = s;
}

__global__ __launch_bounds__(512, 6)
void vq_main(const float* __restrict__ x, const float* __restrict__ ws_f,
             float* __restrict__ out, double* __restrict__ loss_acc) {
    const int tid = threadIdx.x;                               // 0..511
    const int g   = __builtin_amdgcn_readfirstlane(tid >> 6);  // wave id = K-group (SGPR)
    const int r   = tid & 63;                                  // row within block
    const int row = blockIdx.x * ROWS_PER_BLOCK + r;

    // Row in registers as 32 x float2 (64 f32).
    const f32x2* xr = (const f32x2*)(x + (size_t)row * DIM);
    f32x2 f[32];
    #pragma unroll
    for (int j = 0; j < 32; ++j) f[j] = xr[j];

    // r2 = ||f||^2
    f32x2 a = {0.f, 0.f};
    #pragma unroll
    for (int j = 0; j < 32; ++j) a = __builtin_elementwise_fma(f[j], f[j], a);
    const float r2 = a.x + a.y;

    // Wave-uniform codebook chunk -> scalar loads (SGPR operands to the FMAs).
    const float* __restrict__ eg   = ws_f + 1024 + (size_t)g * KCHUNK * DIM;
    const float* __restrict__ en2g = ws_f + 64 + g * KCHUNK;

    float best = 3.402823466e38f;
    int   bk   = 0;
    #pragma unroll 2
    for (int kk = 0; kk < KCHUNK; ++kk) {
        const f32x2* __restrict__ ek = (const f32x2*)(eg + kk * DIM);  // uniform
        f32x2 acc = {0.f, 0.f};
        #pragma unroll
        for (int j = 0; j < 32; ++j)
            acc = __builtin_elementwise_fma(f[j], ek[j], acc);
        const float dot = acc.x + acc.y;
        const float s = (r2 + en2g[kk]) - 2.0f * dot;
        if (s < best) { best = s; bk = kk; }   // strict <: first index wins
    }

    // Pack (distance bits, index). Distances are ~40..100 (positive), so the
    // f32 bit pattern is order-preserving; idx in the low bits makes exact
    // ties resolve to the lowest index == np.argmin first-wins.
    unsigned long long pk =
        ((unsigned long long)__float_as_uint(best) << 32) |
        (unsigned)(g * KCHUNK + bk);

    __shared__ unsigned long long sm[KGROUPS][64];
    sm[g][r] = pk;
    __syncthreads();

    if (g == 0) {
        unsigned long long p = sm[0][r];
        #pragma unroll
        for (int t = 1; t < KGROUPS; ++t) {
            unsigned long long q = sm[t][r];
            p = (q < p) ? q : p;
        }
        const int bidx = (int)(p & 0xffffffffull);

        // Gather code, write out = x + (q - x), accumulate loss.
        const f32x2* q2 = (const f32x2*)(ws_f + 1024) + bidx * 32;
        f32x2* o2 = (f32x2*)(out + (size_t)row * DIM);
        float lsum = 0.0f;
        #pragma unroll
        for (int j = 0; j < 32; ++j) {
            f32x2 q  = q2[j];
            f32x2 xv = f[j];
            f32x2 o;
            float dx;
            dx = q.x - xv.x; o.x = xv.x + dx; lsum = fmaf(dx, dx, lsum);
            dx = q.y - xv.y; o.y = xv.y + dx; lsum = fmaf(dx, dx, lsum);
            o2[j] = o;
        }

        // Wave-level reduction of loss in double, one atomic per block.
        double dl = (double)lsum;
        #pragma unroll
        for (int off = 32; off > 0; off >>= 1)
            dl += __shfl_down(dl, off);
        if (r == 0) atomicAdd(loss_acc, dl);
    }
}

__global__ void vq_fin(const double* __restrict__ loss_acc, float* __restrict__ out) {
    if (threadIdx.x == 0)
        out[N_ROWS * DIM] = (float)(1.25 * loss_acc[0] * (1.0 / (double)(N_ROWS * DIM)));
}

extern "C" void kernel_launch(void* const* d_in, const int* in_sizes, int n_in,
                              void* d_out, int out_size, void* d_ws, size_t ws_size,
                              hipStream_t stream) {
    const float* x   = (const float*)d_in[0];
    const float* emb = (const float*)d_in[1];
    float*  out  = (float*)d_out;
    float*  ws_f = (float*)d_ws;
    double* ws_d = (double*)d_ws;

    vq_prep<<<1, 512, 0, stream>>>(emb, ws_f, ws_d);
    vq_main<<<N_ROWS / ROWS_PER_BLOCK, 512, 0, stream>>>(x, ws_f, out, ws_d);
    vq_fin<<<1, 1, 0, stream>>>(ws_d, out);
}